// Round 8
// baseline (3769.883 us; speedup 1.0000x reference)
//
#include <hip/hip_runtime.h>
#include <hip/hip_bf16.h>

// ---------------- problem constants ----------------
#define NN 500000
#define EE 1250000
#define NP 501760          // padded node count
#define NBLK 489           // scan blocks of 1024

__device__ __forceinline__ float ngnn97_bf2f(unsigned short u) {
  return __uint_as_float(((unsigned int)u) << 16);
}

// ---------------- diagnostic code writer (guard path only) ----------------
__global__ void ngnn97_code(float* __restrict__ out, float v) {
  if (threadIdx.x < 64) out[threadIdx.x] = v;
}

// ---------------- precompute folded weights ----------------
// U[l][k][j], k in [0,128), j in [0,256):
//   k<64  (aggx part): j<192 -> (G @ Wih^T)[k][j] = sum_t G[k][t]*Wih[j][t]; j>=192 -> 0
//   k>=64 (x part):    j<128 -> Whh[j][k-64]; 128<=j<192 -> 0; j>=192 -> Whh[j-64][k-64]
// Ub[l][j]: j<128: bih[j]+bhh[j]; 128..191: bih[j]; 192..255: bhh[j-64]
// V[l][k][d] = tfW[l][d][k]  (for x_cat @ tfW^T)
__global__ __launch_bounds__(256) void ngnn97_pre(
    const float* __restrict__ ggc, const float* __restrict__ wih,
    const float* __restrict__ whh, const float* __restrict__ bih,
    const float* __restrict__ bhh, const float* __restrict__ tfW,
    float* __restrict__ U, float* __restrict__ Ub, float* __restrict__ V) {
  int idx = blockIdx.x * 256 + threadIdx.x;
  if (idx < 163840) {                      // U: 5*128*256
    int l = idx >> 15, r = idx & 32767;
    int k = r >> 8, j = r & 255;
    float v = 0.f;
    if (k < 64) {
      if (j < 192) {
        const float* gp = ggc + l * 4096 + k * 64;
        const float* wp = wih + l * 12288 + j * 64;
        float acc = 0.f;
#pragma unroll
        for (int t = 0; t < 64; t++) acc = fmaf(gp[t], wp[t], acc);
        v = acc;
      }
    } else {
      int k2 = k - 64;
      if (j < 128) v = whh[l * 12288 + j * 64 + k2];
      else if (j >= 192) v = whh[l * 12288 + (j - 64) * 64 + k2];
    }
    U[idx] = v;
  } else if (idx < 163840 + 32768) {       // V: 4*128*64
    int i2 = idx - 163840;
    int l = i2 >> 13, r = i2 & 8191;
    int k = r >> 6, d = r & 63;
    V[i2] = tfW[l * 8192 + d * 128 + k];
  } else if (idx < 163840 + 32768 + 1280) { // Ub: 5*256
    int i2 = idx - 196608;
    int l = i2 >> 8, j = i2 & 255;
    float v;
    if (j < 128)      v = bih[l * 192 + j] + bhh[l * 192 + j];
    else if (j < 192) v = bih[l * 192 + j];
    else              v = bhh[l * 192 + j - 64];
    Ub[i2] = v;
  }
}

// ---------------- CSR build ----------------
__global__ __launch_bounds__(256) void ngnn97_hist(const int* __restrict__ dst, int* __restrict__ counts) {
  int e = blockIdx.x * 256 + threadIdx.x;
  if (e < EE) atomicAdd(&counts[dst[e]], 1);
}

__global__ __launch_bounds__(256) void ngnn97_red(const int* __restrict__ counts, int* __restrict__ bsum) {
  __shared__ int s[256];
  int t = threadIdx.x, base = blockIdx.x * 1024;
  int v = 0;
#pragma unroll
  for (int i = 0; i < 4; i++) v += counts[base + t + i * 256];
  s[t] = v; __syncthreads();
  for (int o = 128; o > 0; o >>= 1) { if (t < o) s[t] += s[t + o]; __syncthreads(); }
  if (t == 0) bsum[blockIdx.x] = s[0];
}

__global__ __launch_bounds__(512) void ngnn97_scan1(const int* __restrict__ bsum, int* __restrict__ boff) {
  __shared__ int s[512];
  int t = threadIdx.x;
  int v = (t < NBLK) ? bsum[t] : 0;
  s[t] = v; __syncthreads();
  for (int o = 1; o < 512; o <<= 1) {
    int a = (t >= o) ? s[t - o] : 0;
    __syncthreads(); s[t] += a; __syncthreads();
  }
  if (t < NBLK) boff[t] = s[t] - v;   // exclusive
}

__global__ __launch_bounds__(256) void ngnn97_scan2(const int* __restrict__ counts, const int* __restrict__ boff,
                                                    int* __restrict__ row_ptr, int* __restrict__ cursor) {
  __shared__ int s[256];
  int t = threadIdx.x, base = blockIdx.x * 1024;
  int4 c = *(const int4*)(counts + base + t * 4);
  int tsum = c.x + c.y + c.z + c.w;
  s[t] = tsum; __syncthreads();
  for (int o = 1; o < 256; o <<= 1) {
    int a = (t >= o) ? s[t - o] : 0;
    __syncthreads(); s[t] += a; __syncthreads();
  }
  int off = boff[blockIdx.x] + s[t] - tsum;
  int4 r;
  r.x = off; r.y = off + c.x; r.z = off + c.x + c.y; r.w = off + c.x + c.y + c.z;
  *(int4*)(row_ptr + base + t * 4) = r;
  *(int4*)(cursor + base + t * 4) = r;
}

__global__ __launch_bounds__(256) void ngnn97_fill(const int* __restrict__ src, const int* __restrict__ dst,
                                                   int* __restrict__ cursor, int* __restrict__ srcs) {
  int e = blockIdx.x * 256 + threadIdx.x;
  if (e < EE) {
    int pos = atomicAdd(&cursor[dst[e]], 1);
    srcs[pos] = src[e];
  }
}

// ---------------- layer-0 embedding ----------------
__global__ __launch_bounds__(256) void ngnn97_embed(const int* __restrict__ z, const float* __restrict__ tab,
                                                    float* __restrict__ x) {
  int idx = blockIdx.x * 256 + threadIdx.x;
  int node = idx >> 4, c4 = (idx & 15) << 2;
  if (node < NN) {
    int zz = z[node];
    float4 v = *(const float4*)(tab + zz * 64 + c4);
    *(float4*)(x + (size_t)node * 64 + c4) = v;
  }
}

// ---------------- neighbor aggregation (gather via CSR) ----------------
__global__ __launch_bounds__(256) void ngnn97_agg(const float* __restrict__ x, const int* __restrict__ row_ptr,
                                                  const int* __restrict__ row_end, const int* __restrict__ srcs,
                                                  __hip_bfloat16* __restrict__ aggx) {
  int t = threadIdx.x;
  int node = blockIdx.x * 4 + (t >> 6);
  int d = t & 63;
  if (node < NN) {
    int b = row_ptr[node], e = row_end[node];
    float acc = 0.f;
    for (int i = b; i < e; i++) {
      int s = srcs[i];
      acc += x[(size_t)s * 64 + d];
    }
    aggx[(size_t)node * 64 + d] = __float2bfloat16(acc);
  }
}

// ---------------- fused GRU (+ next-layer transform) ----------------
// 64 nodes/block, 256 threads: wave g handles nodes g*16..g*16+15, lane j = out col.
__global__ __launch_bounds__(256) void ngnn97_gru(
    float* __restrict__ x, const __hip_bfloat16* __restrict__ aggx,
    const float* __restrict__ U, const float* __restrict__ Ub,
    const float* __restrict__ V, const float* __restrict__ tfb,
    const int* __restrict__ z, const float* __restrict__ ztab,
    int do_transform) {
  __shared__ float A[64][128];            // [aggx | x] rows, 32 KB
  const int t = threadIdx.x;
  const int nbase = blockIdx.x * 64;
  // stage aggx -> cols 0..63
  for (int u0 = t; u0 < 1024; u0 += 256) {
    int r = u0 >> 4, c4 = (u0 & 15) << 2;
    int node = nbase + r;
    float4 v = make_float4(0.f, 0.f, 0.f, 0.f);
    if (node < NN) {
      ushort4 q = *(const ushort4*)((const unsigned short*)aggx + (size_t)node * 64 + c4);
      v = make_float4(ngnn97_bf2f(q.x), ngnn97_bf2f(q.y), ngnn97_bf2f(q.z), ngnn97_bf2f(q.w));
    }
    A[r][c4] = v.x; A[r][c4 + 1] = v.y; A[r][c4 + 2] = v.z; A[r][c4 + 3] = v.w;
  }
  // stage x -> cols 64..127
  for (int u0 = t; u0 < 1024; u0 += 256) {
    int r = u0 >> 4, c4 = (u0 & 15) << 2;
    int node = nbase + r;
    float4 v = make_float4(0.f, 0.f, 0.f, 0.f);
    if (node < NN) v = *(const float4*)(x + (size_t)node * 64 + c4);
    *(float4*)&A[r][64 + c4] = v;
  }
  __syncthreads();

  const int j = t & 63, g = t >> 6;
  const float* Arow = &A[g * 16][0];
  float accR[16], accZ[16], accN[16], accH[16];
  {
    float bR = Ub[j], bZ = Ub[64 + j], bN = Ub[128 + j], bH = Ub[192 + j];
#pragma unroll
    for (int i = 0; i < 16; i++) { accR[i] = bR; accZ[i] = bZ; accN[i] = bN; accH[i] = bH; }
  }
  // K-part 1: aggx (k=0..63) -> r, z, inn
  for (int k = 0; k < 64; k += 4) {
    float b0[4], b1[4], b2[4];
#pragma unroll
    for (int q = 0; q < 4; q++) {
      const float* up = U + (k + q) * 256 + j;
      b0[q] = up[0]; b1[q] = up[64]; b2[q] = up[128];
    }
#pragma unroll
    for (int i = 0; i < 16; i++) {
      float4 a = *(const float4*)&Arow[i * 128 + k];
      accR[i] = fmaf(a.x, b0[0], accR[i]); accR[i] = fmaf(a.y, b0[1], accR[i]);
      accR[i] = fmaf(a.z, b0[2], accR[i]); accR[i] = fmaf(a.w, b0[3], accR[i]);
      accZ[i] = fmaf(a.x, b1[0], accZ[i]); accZ[i] = fmaf(a.y, b1[1], accZ[i]);
      accZ[i] = fmaf(a.z, b1[2], accZ[i]); accZ[i] = fmaf(a.w, b1[3], accZ[i]);
      accN[i] = fmaf(a.x, b2[0], accN[i]); accN[i] = fmaf(a.y, b2[1], accN[i]);
      accN[i] = fmaf(a.z, b2[2], accN[i]); accN[i] = fmaf(a.w, b2[3], accN[i]);
    }
  }
  // K-part 2: x (k=64..127) -> r, z, hn
  for (int k = 64; k < 128; k += 4) {
    float b0[4], b1[4], b3[4];
#pragma unroll
    for (int q = 0; q < 4; q++) {
      const float* up = U + (k + q) * 256 + j;
      b0[q] = up[0]; b1[q] = up[64]; b3[q] = up[192];
    }
#pragma unroll
    for (int i = 0; i < 16; i++) {
      float4 a = *(const float4*)&Arow[i * 128 + k];
      accR[i] = fmaf(a.x, b0[0], accR[i]); accR[i] = fmaf(a.y, b0[1], accR[i]);
      accR[i] = fmaf(a.z, b0[2], accR[i]); accR[i] = fmaf(a.w, b0[3], accR[i]);
      accZ[i] = fmaf(a.x, b1[0], accZ[i]); accZ[i] = fmaf(a.y, b1[1], accZ[i]);
      accZ[i] = fmaf(a.z, b1[2], accZ[i]); accZ[i] = fmaf(a.w, b1[3], accZ[i]);
      accH[i] = fmaf(a.x, b3[0], accH[i]); accH[i] = fmaf(a.y, b3[1], accH[i]);
      accH[i] = fmaf(a.z, b3[2], accH[i]); accH[i] = fmaf(a.w, b3[3], accH[i]);
    }
  }
  // gates
  float xn[16];
#pragma unroll
  for (int i = 0; i < 16; i++) {
    float r = 1.f / (1.f + __expf(-accR[i]));
    float uu = 1.f / (1.f + __expf(-accZ[i]));
    float n = tanhf(accN[i] + r * accH[i]);
    float xo = A[g * 16 + i][64 + j];
    xn[i] = (1.f - uu) * n + uu * xo;
  }
  if (!do_transform) {
#pragma unroll
    for (int i = 0; i < 16; i++) {
      int node = nbase + g * 16 + i;
      if (node < NN) x[(size_t)node * 64 + j] = xn[i];
    }
    return;
  }
  __syncthreads();
  // restage: cols 0..63 = x_new, cols 64..127 = next-layer embedding
#pragma unroll
  for (int i = 0; i < 16; i++) A[g * 16 + i][j] = xn[i];
  for (int i = 0; i < 16; i++) {
    int node = nbase + g * 16 + i;
    int zz = (node < NN) ? z[node] : 0;
    A[g * 16 + i][64 + j] = ztab[zz * 64 + j];
  }
  __syncthreads();
  // transform: x = [x_new | ze] @ V + tfb   ([N,128]@[128,64])
  float acc2[16];
  {
    float bt = tfb[j];
#pragma unroll
    for (int i = 0; i < 16; i++) acc2[i] = bt;
  }
  for (int k = 0; k < 128; k += 4) {
    float b[4];
#pragma unroll
    for (int q = 0; q < 4; q++) b[q] = V[(k + q) * 64 + j];
#pragma unroll
    for (int i = 0; i < 16; i++) {
      float4 a = *(const float4*)&Arow[i * 128 + k];
      acc2[i] = fmaf(a.x, b[0], acc2[i]); acc2[i] = fmaf(a.y, b[1], acc2[i]);
      acc2[i] = fmaf(a.z, b[2], acc2[i]); acc2[i] = fmaf(a.w, b[3], acc2[i]);
    }
  }
#pragma unroll
  for (int i = 0; i < 16; i++) {
    int node = nbase + g * 16 + i;
    if (node < NN) x[(size_t)node * 64 + j] = acc2[i];
  }
}

// ---------------- pooling: sum x rows by graph id (16 KB LDS atomic variant) ----------------
__global__ __launch_bounds__(256) void ngnn97_pool(const float* __restrict__ x, const int* __restrict__ n2s,
                                                   const int* __restrict__ s2g, float* __restrict__ gpool) {
  __shared__ float gacc[64][64];
  int t = threadIdx.x, w = t >> 6, lane = t & 63;
  for (int i = t; i < 4096; i += 256) ((float*)gacc)[i] = 0.f;
  __syncthreads();
  int base = blockIdx.x * 2048;
  for (int it = 0; it < 512; it++) {
    int node = base + it * 4 + w;
    if (node < NN) {
      int g = s2g[n2s[node]];
      atomicAdd(&gacc[g][lane], x[(size_t)node * 64 + lane]);
    }
  }
  __syncthreads();
  for (int i = t; i < 4096; i += 256) {
    float v = ((float*)gacc)[i];
    if (v != 0.f) atomicAdd(&gpool[i], v);
  }
}

// ---------------- MLP head (output: FLOAT32, [G,1] = 64 floats) ----------------
__global__ __launch_bounds__(256) void ngnn97_head(
    const float* __restrict__ gpool,
    const float* __restrict__ W1, const float* __restrict__ b1,
    const float* __restrict__ W2, const float* __restrict__ b2,
    const float* __restrict__ W3, const float* __restrict__ b3,
    float* __restrict__ out) {
  __shared__ float gp[4096];
  __shared__ float h1[2048];
  __shared__ float h2[1024];
  int t = threadIdx.x;
  for (int i = t; i < 4096; i += 256) gp[i] = gpool[i];
  __syncthreads();
  for (int i = t; i < 2048; i += 256) {
    int g = i >> 5, o = i & 31;
    float a = b1[o];
    for (int d = 0; d < 64; d++) a = fmaf(gp[g * 64 + d], W1[o * 64 + d], a);
    h1[i] = (a > 0.f) ? a : (__expf(a) - 1.f);
  }
  __syncthreads();
  for (int i = t; i < 1024; i += 256) {
    int g = i >> 4, o = i & 15;
    float a = b2[o];
    for (int d = 0; d < 32; d++) a = fmaf(h1[g * 32 + d], W2[o * 32 + d], a);
    h2[i] = (a > 0.f) ? a : (__expf(a) - 1.f);
  }
  __syncthreads();
  if (t < 64) {
    float a = b3[0];
    for (int d = 0; d < 16; d++) a = fmaf(h2[t * 16 + d], W3[d], a);
    out[t] = a;   // f32 store — the reference output dtype is float32
  }
}

// ---------------- workspace layout (byte offsets) ----------------
// First-submission map: WS_NEED = 203,833,152, proven to pass the ws guard.
#define OFF_X    ((size_t)0)                          // N*64 f32  = 128,000,000
#define OFF_AGG  ((size_t)128000000)                  // N*64 bf16 =  64,000,000
#define OFF_CNT  (OFF_AGG + (size_t)64000000)         // NP int
#define OFF_ROW  (OFF_CNT + (size_t)NP * 4)
#define OFF_CUR  (OFF_ROW + (size_t)NP * 4)
#define OFF_SRC  (OFF_CUR + (size_t)NP * 4)           // E int
#define OFF_BSUM (OFF_SRC + (size_t)EE * 4)
#define OFF_BOFF (OFF_BSUM + (size_t)2048)
#define OFF_U    (OFF_BOFF + (size_t)2048)            // 5*128*256 f32
#define OFF_UB   (OFF_U + (size_t)655360)             // 5*256 f32
#define OFF_V    (OFF_UB + (size_t)5120)              // 4*128*64 f32
#define OFF_GP   (OFF_V + (size_t)131072)             // 64*64 f32
#define WS_NEED  (OFF_GP + (size_t)16384)             // = 203,833,152

extern "C" void kernel_launch(void* const* d_in, const int* in_sizes, int n_in,
                              void* d_out, int out_size, void* d_ws, size_t ws_size,
                              hipStream_t stream) {
  float* out = (float*)d_out;   // reference output is float32 [G,1]
  if (ws_size < WS_NEED) {
    ngnn97_code<<<1, 64, 0, stream>>>(out, 7.0f);   // err ~6-7 => guard tripped
    return;
  }

  const int* z    = (const int*)d_in[0];
  const int* ei   = (const int*)d_in[1];
  const int* n2s  = (const int*)d_in[2];
  const int* s2g  = (const int*)d_in[3];
  const float* ztab = (const float*)d_in[4];
  const float* tfW  = (const float*)d_in[5];
  const float* tfb  = (const float*)d_in[6];
  const float* ggc  = (const float*)d_in[7];
  const float* wih  = (const float*)d_in[8];
  const float* whh  = (const float*)d_in[9];
  const float* bih  = (const float*)d_in[10];
  const float* bhh  = (const float*)d_in[11];
  const float* W1   = (const float*)d_in[12];
  const float* b1   = (const float*)d_in[13];
  const float* W2   = (const float*)d_in[14];
  const float* b2   = (const float*)d_in[15];
  const float* W3   = (const float*)d_in[16];
  const float* b3   = (const float*)d_in[17];

  char* ws = (char*)d_ws;
  float*          x      = (float*)(ws + OFF_X);
  __hip_bfloat16* aggx   = (__hip_bfloat16*)(ws + OFF_AGG);
  int*            counts = (int*)(ws + OFF_CNT);
  int*            rowp   = (int*)(ws + OFF_ROW);
  int*            curs   = (int*)(ws + OFF_CUR);
  int*            srcs   = (int*)(ws + OFF_SRC);
  int*            bsum   = (int*)(ws + OFF_BSUM);
  int*            boff   = (int*)(ws + OFF_BOFF);
  float*          U      = (float*)(ws + OFF_U);
  float*          Ub     = (float*)(ws + OFF_UB);
  float*          V      = (float*)(ws + OFF_V);
  float*          gpool  = (float*)(ws + OFF_GP);

  hipMemsetAsync(counts, 0, (size_t)NP * 4, stream);
  hipMemsetAsync(gpool, 0, 16384, stream);

  ngnn97_pre<<<773, 256, 0, stream>>>(ggc, wih, whh, bih, bhh, tfW, U, Ub, V);

  // CSR by dst
  const int* srcp = ei;
  const int* dstp = ei + EE;
  ngnn97_hist<<<(EE + 255) / 256, 256, 0, stream>>>(dstp, counts);
  ngnn97_red<<<NBLK, 256, 0, stream>>>(counts, bsum);
  ngnn97_scan1<<<1, 512, 0, stream>>>(bsum, boff);
  ngnn97_scan2<<<NBLK, 256, 0, stream>>>(counts, boff, rowp, curs);
  ngnn97_fill<<<(EE + 255) / 256, 256, 0, stream>>>(srcp, dstp, curs, srcs);
  // after ngnn97_fill, curs[i] == row end

  ngnn97_embed<<<(NN * 16 + 255) / 256, 256, 0, stream>>>(z, ztab, x);

  for (int l = 0; l < 5; l++) {
    ngnn97_agg<<<(NN + 3) / 4, 256, 0, stream>>>(x, rowp, curs, srcs, aggx);
    ngnn97_gru<<<(NN + 63) / 64, 256, 0, stream>>>(
        x, aggx, U + (size_t)l * 32768, Ub + (size_t)l * 256,
        V + (size_t)(l < 4 ? l : 0) * 8192, tfb + (size_t)(l < 4 ? l : 0) * 64,
        z, ztab + (size_t)(l < 4 ? l + 1 : 0) * 6400, (l < 4) ? 1 : 0);
  }

  ngnn97_pool<<<(NN + 2047) / 2048, 256, 0, stream>>>(x, n2s, s2g, gpool);
  ngnn97_head<<<1, 256, 0, stream>>>(gpool, W1, b1, W2, b2, W3, b3, out);
}

// Round 9
// 2872.580 us; speedup vs baseline: 1.3124x; 1.3124x over previous
//
#include <hip/hip_runtime.h>
#include <hip/hip_bf16.h>

// ---------------- problem constants ----------------
#define NN 500000
#define EE 1250000
#define NP 501760          // padded node count
#define NBLK 489           // scan blocks of 1024

typedef __attribute__((ext_vector_type(8))) short bf16x8;
typedef __attribute__((ext_vector_type(4))) float f32x4;

__device__ __forceinline__ float ngnn97_bf2f(unsigned short u) {
  return __uint_as_float(((unsigned int)u) << 16);
}
__device__ __forceinline__ unsigned short ngnn97_f2bf(float f) {
  union { __hip_bfloat16 b; unsigned short u; } cv;
  cv.b = __float2bfloat16(f);
  return cv.u;
}

// ---------------- diagnostic code writer (guard path only) ----------------
__global__ void ngnn97_code(float* __restrict__ out, float v) {
  if (threadIdx.x < 64) out[threadIdx.x] = v;
}

// ---------------- precompute folded weights (bf16, MFMA-B layout) ----------------
// Ubt[l][n][k] (n=0..255 output col, k=0..127 input dim), bf16, k-consecutive:
//   k<64  (aggx part): n<192 -> (G @ Wih^T)[k][n]; else 0
//   k>=64 (x part):    n<128 -> Whh[n][k-64]; 128<=n<192 -> 0; n>=192 -> Whh[n-64][k-64]
// Vbt[l][d][k] = tfW[l][d][k]  (already k-consecutive row-major -> direct cast)
// Ub[l][j]: j<128: bih+bhh; 128..191: bih; 192..255: bhh[j-64]
__global__ __launch_bounds__(256) void ngnn97_pre(
    const float* __restrict__ ggc, const float* __restrict__ wih,
    const float* __restrict__ whh, const float* __restrict__ bih,
    const float* __restrict__ bhh, const float* __restrict__ tfW,
    unsigned short* __restrict__ Ubt, float* __restrict__ Ub,
    unsigned short* __restrict__ Vbt) {
  int idx = blockIdx.x * 256 + threadIdx.x;
  if (idx < 163840) {                      // Ubt: 5*256*128
    int l = idx >> 15, r = idx & 32767;
    int n = r >> 7, k = r & 127;
    float v = 0.f;
    if (k < 64) {
      if (n < 192) {
        const float* gp = ggc + l * 4096 + k * 64;
        const float* wp = wih + l * 12288 + n * 64;
        float acc = 0.f;
#pragma unroll
        for (int t2 = 0; t2 < 64; t2++) acc = fmaf(gp[t2], wp[t2], acc);
        v = acc;
      }
    } else {
      int k2 = k - 64;
      if (n < 128) v = whh[l * 12288 + n * 64 + k2];
      else if (n >= 192) v = whh[l * 12288 + (n - 64) * 64 + k2];
    }
    Ubt[idx] = ngnn97_f2bf(v);
  } else if (idx < 163840 + 32768) {       // Vbt: 4*64*128 (= tfW flat)
    int i2 = idx - 163840;
    Vbt[i2] = ngnn97_f2bf(tfW[i2]);
  } else if (idx < 163840 + 32768 + 1280) { // Ub: 5*256
    int i2 = idx - 196608;
    int l = i2 >> 8, j = i2 & 255;
    float v;
    if (j < 128)      v = bih[l * 192 + j] + bhh[l * 192 + j];
    else if (j < 192) v = bih[l * 192 + j];
    else              v = bhh[l * 192 + j - 64];
    Ub[i2] = v;
  }
}

// ---------------- CSR build ----------------
__global__ __launch_bounds__(256) void ngnn97_hist(const int* __restrict__ dst, int* __restrict__ counts) {
  int e = blockIdx.x * 256 + threadIdx.x;
  if (e < EE) atomicAdd(&counts[dst[e]], 1);
}

__global__ __launch_bounds__(256) void ngnn97_red(const int* __restrict__ counts, int* __restrict__ bsum) {
  __shared__ int s[256];
  int t = threadIdx.x, base = blockIdx.x * 1024;
  int v = 0;
#pragma unroll
  for (int i = 0; i < 4; i++) v += counts[base + t + i * 256];
  s[t] = v; __syncthreads();
  for (int o = 128; o > 0; o >>= 1) { if (t < o) s[t] += s[t + o]; __syncthreads(); }
  if (t == 0) bsum[blockIdx.x] = s[0];
}

__global__ __launch_bounds__(512) void ngnn97_scan1(const int* __restrict__ bsum, int* __restrict__ boff) {
  __shared__ int s[512];
  int t = threadIdx.x;
  int v = (t < NBLK) ? bsum[t] : 0;
  s[t] = v; __syncthreads();
  for (int o = 1; o < 512; o <<= 1) {
    int a = (t >= o) ? s[t - o] : 0;
    __syncthreads(); s[t] += a; __syncthreads();
  }
  if (t < NBLK) boff[t] = s[t] - v;   // exclusive
}

__global__ __launch_bounds__(256) void ngnn97_scan2(const int* __restrict__ counts, const int* __restrict__ boff,
                                                    int* __restrict__ row_ptr, int* __restrict__ cursor) {
  __shared__ int s[256];
  int t = threadIdx.x, base = blockIdx.x * 1024;
  int4 c = *(const int4*)(counts + base + t * 4);
  int tsum = c.x + c.y + c.z + c.w;
  s[t] = tsum; __syncthreads();
  for (int o = 1; o < 256; o <<= 1) {
    int a = (t >= o) ? s[t - o] : 0;
    __syncthreads(); s[t] += a; __syncthreads();
  }
  int off = boff[blockIdx.x] + s[t] - tsum;
  int4 r;
  r.x = off; r.y = off + c.x; r.z = off + c.x + c.y; r.w = off + c.x + c.y + c.z;
  *(int4*)(row_ptr + base + t * 4) = r;
  *(int4*)(cursor + base + t * 4) = r;
}

__global__ __launch_bounds__(256) void ngnn97_fill(const int* __restrict__ src, const int* __restrict__ dst,
                                                   int* __restrict__ cursor, int* __restrict__ srcs) {
  int e = blockIdx.x * 256 + threadIdx.x;
  if (e < EE) {
    int pos = atomicAdd(&cursor[dst[e]], 1);
    srcs[pos] = src[e];
  }
}

// ---------------- layer-0 embedding ----------------
__global__ __launch_bounds__(256) void ngnn97_embed(const int* __restrict__ z, const float* __restrict__ tab,
                                                    float* __restrict__ x) {
  int idx = blockIdx.x * 256 + threadIdx.x;
  int node = idx >> 4, c4 = (idx & 15) << 2;
  if (node < NN) {
    int zz = z[node];
    float4 v = *(const float4*)(tab + zz * 64 + c4);
    *(float4*)(x + (size_t)node * 64 + c4) = v;
  }
}

// ---------------- neighbor aggregation (gather via CSR) ----------------
__global__ __launch_bounds__(256) void ngnn97_agg(const float* __restrict__ x, const int* __restrict__ row_ptr,
                                                  const int* __restrict__ row_end, const int* __restrict__ srcs,
                                                  __hip_bfloat16* __restrict__ aggx) {
  int t = threadIdx.x;
  int node = blockIdx.x * 4 + (t >> 6);
  int d = t & 63;
  if (node < NN) {
    int b = row_ptr[node], e = row_end[node];
    float acc = 0.f;
    for (int i = b; i < e; i++) {
      int s = srcs[i];
      acc += x[(size_t)s * 64 + d];
    }
    aggx[(size_t)node * 64 + d] = __float2bfloat16(acc);
  }
}

// ---------------- fused GRU via MFMA (+ next-layer transform) ----------------
// Block = 64 nodes, 4 waves. Wave w owns node strip [nbase+16w, nbase+16w+16).
// Y[64x256] = A[64x128] @ Ubt^T via mfma_f32_16x16x32_bf16; A = [aggx | bf16(x)].
// Gate update is lane-local (R/Z/N/H share lane+reg across the 4 gate tiles).
// Transform reuses Abuf strip-locally: A2 = [bf16(xn) | bf16(ze)] @ Vbt^T.
__global__ __launch_bounds__(256) void ngnn97_gru(
    float* __restrict__ x, const unsigned short* __restrict__ aggx,
    const unsigned short* __restrict__ Ubt, const float* __restrict__ Ub,
    const unsigned short* __restrict__ Vbt, const float* __restrict__ tfb,
    const int* __restrict__ z, const float* __restrict__ ztab,
    int do_transform) {
  __shared__ unsigned short Abuf[64 * 136];   // 64 rows x 128 cols bf16, pad 8 (17.4 KB)
  const int t = threadIdx.x;
  const int lane = t & 63, w = t >> 6;
  const int ncol = lane & 15, quad = lane >> 4;
  const int nbase = blockIdx.x * 64;

  // ---- stage A1: cols 0..63 = aggx (bf16 copy), cols 64..127 = bf16(x) ----
#pragma unroll
  for (int i = 0; i < 4; i++) {
    int chunk = i * 256 + t;                 // 0..1023
    int r = chunk >> 4, c4 = (chunk & 15) << 2;
    int node = nbase + r;
    ushort4 q = make_ushort4(0, 0, 0, 0);
    if (node < NN) q = *(const ushort4*)(aggx + (size_t)node * 64 + c4);
    *(ushort4*)(Abuf + r * 136 + c4) = q;
  }
#pragma unroll
  for (int i = 0; i < 4; i++) {
    int chunk = i * 256 + t;
    int r = chunk >> 4, c4 = (chunk & 15) << 2;
    int node = nbase + r;
    float4 v = make_float4(0.f, 0.f, 0.f, 0.f);
    if (node < NN) v = *(const float4*)(x + (size_t)node * 64 + c4);
    ushort4 q;
    q.x = ngnn97_f2bf(v.x); q.y = ngnn97_f2bf(v.y);
    q.z = ngnn97_f2bf(v.z); q.w = ngnn97_f2bf(v.w);
    *(ushort4*)(Abuf + r * 136 + 64 + c4) = q;
  }
  __syncthreads();

  // ---- A-frags for this wave's strip (m = 16w + ncol), 4 K-chunks ----
  bf16x8 afr[4];
  {
    const unsigned short* ap = Abuf + (16 * w + ncol) * 136 + quad * 8;
#pragma unroll
    for (int kc = 0; kc < 4; kc++) afr[kc] = *(const bf16x8*)(ap + kc * 32);
  }

  // ---- gate GEMM + GRU update, 16 cols per c-iteration ----
  float xn[4][4];                           // [c][reg]
#pragma unroll
  for (int c = 0; c < 4; c++) {
    f32x4 aR = {0.f, 0.f, 0.f, 0.f}, aZ = aR, aN = aR, aH = aR;
#pragma unroll
    for (int kc = 0; kc < 4; kc++) {
      int koff = quad * 8 + kc * 32;
      const unsigned short* ub = Ubt + (size_t)(c * 16 + ncol) * 128 + koff;
      bf16x8 bR = *(const bf16x8*)(ub);
      bf16x8 bZ = *(const bf16x8*)(ub + 64 * 128);
      bf16x8 bN = *(const bf16x8*)(ub + 128 * 128);
      bf16x8 bH = *(const bf16x8*)(ub + 192 * 128);
      aR = __builtin_amdgcn_mfma_f32_16x16x32_bf16(afr[kc], bR, aR, 0, 0, 0);
      aZ = __builtin_amdgcn_mfma_f32_16x16x32_bf16(afr[kc], bZ, aZ, 0, 0, 0);
      aN = __builtin_amdgcn_mfma_f32_16x16x32_bf16(afr[kc], bN, aN, 0, 0, 0);
      aH = __builtin_amdgcn_mfma_f32_16x16x32_bf16(afr[kc], bH, aH, 0, 0, 0);
    }
    int j = c * 16 + ncol;
    float bR = Ub[j], bZ = Ub[64 + j], bN = Ub[128 + j], bH = Ub[192 + j];
#pragma unroll
    for (int r = 0; r < 4; r++) {
      int node = nbase + 16 * w + quad * 4 + r;
      float R = aR[r] + bR, Z = aZ[r] + bZ, Nv = aN[r] + bN, H = aH[r] + bH;
      float rg = 1.f / (1.f + __expf(-R));
      float ug = 1.f / (1.f + __expf(-Z));
      float nn = tanhf(Nv + rg * H);
      float xo = (node < NN) ? x[(size_t)node * 64 + j] : 0.f;
      xn[c][r] = (1.f - ug) * nn + ug * xo;
    }
  }

  if (!do_transform) {
#pragma unroll
    for (int c = 0; c < 4; c++)
#pragma unroll
      for (int r = 0; r < 4; r++) {
        int node = nbase + 16 * w + quad * 4 + r;
        if (node < NN) x[(size_t)node * 64 + c * 16 + ncol] = xn[c][r];
      }
    return;
  }

  // ---- restage A2 over Abuf (strip-local rows only -> no barrier needed) ----
#pragma unroll
  for (int c = 0; c < 4; c++)
#pragma unroll
    for (int r = 0; r < 4; r++)
      Abuf[(16 * w + quad * 4 + r) * 136 + c * 16 + ncol] = ngnn97_f2bf(xn[c][r]);
#pragma unroll
  for (int i = 0; i < 16; i++) {
    int elem = i * 64 + lane;               // 0..1023 over 16 rows x 64 cols
    int rl = elem >> 6, col = elem & 63;
    int node = nbase + 16 * w + rl;
    int zz = (node < NN) ? z[node] : 0;
    Abuf[(16 * w + rl) * 136 + 64 + col] = ngnn97_f2bf(ztab[zz * 64 + col]);
  }

  // ---- transform GEMM: x = A2 @ Vbt^T + tfb ----
  bf16x8 afr2[4];
  {
    const unsigned short* ap2 = Abuf + (16 * w + ncol) * 136 + quad * 8;
#pragma unroll
    for (int kc = 0; kc < 4; kc++) afr2[kc] = *(const bf16x8*)(ap2 + kc * 32);
  }
#pragma unroll
  for (int c2 = 0; c2 < 4; c2++) {
    f32x4 acc = {0.f, 0.f, 0.f, 0.f};
#pragma unroll
    for (int kc = 0; kc < 4; kc++) {
      bf16x8 bV = *(const bf16x8*)(Vbt + (size_t)(c2 * 16 + ncol) * 128 + quad * 8 + kc * 32);
      acc = __builtin_amdgcn_mfma_f32_16x16x32_bf16(afr2[kc], bV, acc, 0, 0, 0);
    }
    int j = c2 * 16 + ncol;
    float bt = tfb[j];
#pragma unroll
    for (int r = 0; r < 4; r++) {
      int node = nbase + 16 * w + quad * 4 + r;
      if (node < NN) x[(size_t)node * 64 + j] = acc[r] + bt;
    }
  }
}

// ---------------- pooling: sum x rows by graph id (16 KB LDS atomic variant) ----------------
__global__ __launch_bounds__(256) void ngnn97_pool(const float* __restrict__ x, const int* __restrict__ n2s,
                                                   const int* __restrict__ s2g, float* __restrict__ gpool) {
  __shared__ float gacc[64][64];
  int t = threadIdx.x, w = t >> 6, lane = t & 63;
  for (int i = t; i < 4096; i += 256) ((float*)gacc)[i] = 0.f;
  __syncthreads();
  int base = blockIdx.x * 2048;
  for (int it = 0; it < 512; it++) {
    int node = base + it * 4 + w;
    if (node < NN) {
      int g = s2g[n2s[node]];
      atomicAdd(&gacc[g][lane], x[(size_t)node * 64 + lane]);
    }
  }
  __syncthreads();
  for (int i = t; i < 4096; i += 256) {
    float v = ((float*)gacc)[i];
    if (v != 0.f) atomicAdd(&gpool[i], v);
  }
}

// ---------------- MLP head (output: float32 [G,1]) ----------------
__global__ __launch_bounds__(256) void ngnn97_head(
    const float* __restrict__ gpool,
    const float* __restrict__ W1, const float* __restrict__ b1,
    const float* __restrict__ W2, const float* __restrict__ b2,
    const float* __restrict__ W3, const float* __restrict__ b3,
    float* __restrict__ out) {
  __shared__ float gp[4096];
  __shared__ float h1[2048];
  __shared__ float h2[1024];
  int t = threadIdx.x;
  for (int i = t; i < 4096; i += 256) gp[i] = gpool[i];
  __syncthreads();
  for (int i = t; i < 2048; i += 256) {
    int g = i >> 5, o = i & 31;
    float a = b1[o];
    for (int d = 0; d < 64; d++) a = fmaf(gp[g * 64 + d], W1[o * 64 + d], a);
    h1[i] = (a > 0.f) ? a : (__expf(a) - 1.f);
  }
  __syncthreads();
  for (int i = t; i < 1024; i += 256) {
    int g = i >> 4, o = i & 15;
    float a = b2[o];
    for (int d = 0; d < 32; d++) a = fmaf(h1[g * 32 + d], W2[o * 32 + d], a);
    h2[i] = (a > 0.f) ? a : (__expf(a) - 1.f);
  }
  __syncthreads();
  if (t < 64) {
    float a = b3[0];
    for (int d = 0; d < 16; d++) a = fmaf(h2[t * 16 + d], W3[d], a);
    out[t] = a;
  }
}

// ---------------- workspace layout (byte offsets) ----------------
// Proven map: WS_NEED = 203,833,152 passes the harness guard.
// Ubt (bf16 327,680 B) lives in the old U slot (655,360 B); Vbt (65,536 B) in
// the old V slot (131,072 B) — offsets unchanged, usage shrank.
#define OFF_X    ((size_t)0)                          // N*64 f32  = 128,000,000
#define OFF_AGG  ((size_t)128000000)                  // N*64 bf16 =  64,000,000
#define OFF_CNT  (OFF_AGG + (size_t)64000000)         // NP int
#define OFF_ROW  (OFF_CNT + (size_t)NP * 4)
#define OFF_CUR  (OFF_ROW + (size_t)NP * 4)
#define OFF_SRC  (OFF_CUR + (size_t)NP * 4)           // E int
#define OFF_BSUM (OFF_SRC + (size_t)EE * 4)
#define OFF_BOFF (OFF_BSUM + (size_t)2048)
#define OFF_U    (OFF_BOFF + (size_t)2048)            // Ubt bf16 5*256*128
#define OFF_UB   (OFF_U + (size_t)655360)             // Ub f32 5*256
#define OFF_V    (OFF_UB + (size_t)5120)              // Vbt bf16 4*64*128
#define OFF_GP   (OFF_V + (size_t)131072)             // 64*64 f32
#define WS_NEED  (OFF_GP + (size_t)16384)             // = 203,833,152

extern "C" void kernel_launch(void* const* d_in, const int* in_sizes, int n_in,
                              void* d_out, int out_size, void* d_ws, size_t ws_size,
                              hipStream_t stream) {
  float* out = (float*)d_out;   // reference output is float32 [G,1]
  if (ws_size < WS_NEED) {
    ngnn97_code<<<1, 64, 0, stream>>>(out, 7.0f);   // err ~6-7 => guard tripped
    return;
  }

  const int* z    = (const int*)d_in[0];
  const int* ei   = (const int*)d_in[1];
  const int* n2s  = (const int*)d_in[2];
  const int* s2g  = (const int*)d_in[3];
  const float* ztab = (const float*)d_in[4];
  const float* tfW  = (const float*)d_in[5];
  const float* tfb  = (const float*)d_in[6];
  const float* ggc  = (const float*)d_in[7];
  const float* wih  = (const float*)d_in[8];
  const float* whh  = (const float*)d_in[9];
  const float* bih  = (const float*)d_in[10];
  const float* bhh  = (const float*)d_in[11];
  const float* W1   = (const float*)d_in[12];
  const float* b1   = (const float*)d_in[13];
  const float* W2   = (const float*)d_in[14];
  const float* b2   = (const float*)d_in[15];
  const float* W3   = (const float*)d_in[16];
  const float* b3   = (const float*)d_in[17];

  char* ws = (char*)d_ws;
  float*          x      = (float*)(ws + OFF_X);
  unsigned short* aggx   = (unsigned short*)(ws + OFF_AGG);
  int*            counts = (int*)(ws + OFF_CNT);
  int*            rowp   = (int*)(ws + OFF_ROW);
  int*            curs   = (int*)(ws + OFF_CUR);
  int*            srcs   = (int*)(ws + OFF_SRC);
  int*            bsum   = (int*)(ws + OFF_BSUM);
  int*            boff   = (int*)(ws + OFF_BOFF);
  unsigned short* Ubt    = (unsigned short*)(ws + OFF_U);
  float*          Ub     = (float*)(ws + OFF_UB);
  unsigned short* Vbt    = (unsigned short*)(ws + OFF_V);
  float*          gpool  = (float*)(ws + OFF_GP);

  hipMemsetAsync(counts, 0, (size_t)NP * 4, stream);
  hipMemsetAsync(gpool, 0, 16384, stream);

  ngnn97_pre<<<774, 256, 0, stream>>>(ggc, wih, whh, bih, bhh, tfW, Ubt, Ub, Vbt);

  // CSR by dst
  const int* srcp = ei;
  const int* dstp = ei + EE;
  ngnn97_hist<<<(EE + 255) / 256, 256, 0, stream>>>(dstp, counts);
  ngnn97_red<<<NBLK, 256, 0, stream>>>(counts, bsum);
  ngnn97_scan1<<<1, 512, 0, stream>>>(bsum, boff);
  ngnn97_scan2<<<NBLK, 256, 0, stream>>>(counts, boff, rowp, curs);
  ngnn97_fill<<<(EE + 255) / 256, 256, 0, stream>>>(srcp, dstp, curs, srcs);
  // after ngnn97_fill, curs[i] == row end

  ngnn97_embed<<<(NN * 16 + 255) / 256, 256, 0, stream>>>(z, ztab, x);

  for (int l = 0; l < 5; l++) {
    ngnn97_agg<<<(NN + 3) / 4, 256, 0, stream>>>(x, rowp, curs, srcs, (__hip_bfloat16*)aggx);
    ngnn97_gru<<<(NN + 63) / 64, 256, 0, stream>>>(
        x, aggx, Ubt + (size_t)l * 32768, Ub + (size_t)l * 256,
        Vbt + (size_t)(l < 4 ? l : 0) * 8192, tfb + (size_t)(l < 4 ? l : 0) * 64,
        z, ztab + (size_t)(l < 4 ? l + 1 : 0) * 6400, (l < 4) ? 1 : 0);
  }

  ngnn97_pool<<<(NN + 2047) / 2048, 256, 0, stream>>>(x, n2s, s2g, gpool);
  ngnn97_head<<<1, 256, 0, stream>>>(gpool, W1, b1, W2, b2, W3, b3, out);
}

// Round 10
// 2112.913 us; speedup vs baseline: 1.7842x; 1.3595x over previous
//
#include <hip/hip_runtime.h>
#include <hip/hip_bf16.h>

// ---------------- problem constants ----------------
#define NN 500000
#define EE 1250000
#define NP 501760          // padded node count
#define NBLK 489           // scan blocks of 1024

typedef __attribute__((ext_vector_type(8))) short bf16x8;
typedef __attribute__((ext_vector_type(4))) float f32x4;

__device__ __forceinline__ float ngnn97_bf2f(unsigned short u) {
  return __uint_as_float(((unsigned int)u) << 16);
}
__device__ __forceinline__ unsigned short ngnn97_f2bf(float f) {
  union { __hip_bfloat16 b; unsigned short u; } cv;
  cv.b = __float2bfloat16(f);
  return cv.u;
}

// ---------------- diagnostic code writer (guard path only) ----------------
__global__ void ngnn97_code(float* __restrict__ out, float v) {
  if (threadIdx.x < 64) out[threadIdx.x] = v;
}

// ---------------- precompute folded weights (bf16, MFMA-B layout) ----------------
// Ubt[l][n][k]: n=0..255 (R:0-63,Z:64-127,N:128-191,H:192-255), k=0..127.
//   k<64 (aggx): R,Z,N nonzero; H zero.  k>=64 (x): R,Z,H nonzero; N zero.
// Vbt[l][d][k] = tfW[l][d][k].  Ub biases as before.
__global__ __launch_bounds__(256) void ngnn97_pre(
    const float* __restrict__ ggc, const float* __restrict__ wih,
    const float* __restrict__ whh, const float* __restrict__ bih,
    const float* __restrict__ bhh, const float* __restrict__ tfW,
    unsigned short* __restrict__ Ubt, float* __restrict__ Ub,
    unsigned short* __restrict__ Vbt) {
  int idx = blockIdx.x * 256 + threadIdx.x;
  if (idx < 163840) {                      // Ubt: 5*256*128
    int l = idx >> 15, r = idx & 32767;
    int n = r >> 7, k = r & 127;
    float v = 0.f;
    if (k < 64) {
      if (n < 192) {
        const float* gp = ggc + l * 4096 + k * 64;
        const float* wp = wih + l * 12288 + n * 64;
        float acc = 0.f;
#pragma unroll
        for (int t2 = 0; t2 < 64; t2++) acc = fmaf(gp[t2], wp[t2], acc);
        v = acc;
      }
    } else {
      int k2 = k - 64;
      if (n < 128) v = whh[l * 12288 + n * 64 + k2];
      else if (n >= 192) v = whh[l * 12288 + (n - 64) * 64 + k2];
    }
    Ubt[idx] = ngnn97_f2bf(v);
  } else if (idx < 163840 + 32768) {       // Vbt: 4*64*128 (= tfW flat)
    int i2 = idx - 163840;
    Vbt[i2] = ngnn97_f2bf(tfW[i2]);
  } else if (idx < 163840 + 32768 + 1280) { // Ub: 5*256
    int i2 = idx - 196608;
    int l = i2 >> 8, j = i2 & 255;
    float v;
    if (j < 128)      v = bih[l * 192 + j] + bhh[l * 192 + j];
    else if (j < 192) v = bih[l * 192 + j];
    else              v = bhh[l * 192 + j - 64];
    Ub[i2] = v;
  }
}

// ---------------- CSR build ----------------
__global__ __launch_bounds__(256) void ngnn97_hist(const int* __restrict__ dst, int* __restrict__ counts) {
  int e = blockIdx.x * 256 + threadIdx.x;
  if (e < EE) atomicAdd(&counts[dst[e]], 1);
}

__global__ __launch_bounds__(256) void ngnn97_red(const int* __restrict__ counts, int* __restrict__ bsum) {
  __shared__ int s[256];
  int t = threadIdx.x, base = blockIdx.x * 1024;
  int v = 0;
#pragma unroll
  for (int i = 0; i < 4; i++) v += counts[base + t + i * 256];
  s[t] = v; __syncthreads();
  for (int o = 128; o > 0; o >>= 1) { if (t < o) s[t] += s[t + o]; __syncthreads(); }
  if (t == 0) bsum[blockIdx.x] = s[0];
}

__global__ __launch_bounds__(512) void ngnn97_scan1(const int* __restrict__ bsum, int* __restrict__ boff) {
  __shared__ int s[512];
  int t = threadIdx.x;
  int v = (t < NBLK) ? bsum[t] : 0;
  s[t] = v; __syncthreads();
  for (int o = 1; o < 512; o <<= 1) {
    int a = (t >= o) ? s[t - o] : 0;
    __syncthreads(); s[t] += a; __syncthreads();
  }
  if (t < NBLK) boff[t] = s[t] - v;   // exclusive
}

__global__ __launch_bounds__(256) void ngnn97_scan2(const int* __restrict__ counts, const int* __restrict__ boff,
                                                    int* __restrict__ row_ptr, int* __restrict__ cursor) {
  __shared__ int s[256];
  int t = threadIdx.x, base = blockIdx.x * 1024;
  int4 c = *(const int4*)(counts + base + t * 4);
  int tsum = c.x + c.y + c.z + c.w;
  s[t] = tsum; __syncthreads();
  for (int o = 1; o < 256; o <<= 1) {
    int a = (t >= o) ? s[t - o] : 0;
    __syncthreads(); s[t] += a; __syncthreads();
  }
  int off = boff[blockIdx.x] + s[t] - tsum;
  int4 r;
  r.x = off; r.y = off + c.x; r.z = off + c.x + c.y; r.w = off + c.x + c.y + c.z;
  *(int4*)(row_ptr + base + t * 4) = r;
  *(int4*)(cursor + base + t * 4) = r;
}

__global__ __launch_bounds__(256) void ngnn97_fill(const int* __restrict__ src, const int* __restrict__ dst,
                                                   int* __restrict__ cursor, int* __restrict__ srcs) {
  int e = blockIdx.x * 256 + threadIdx.x;
  if (e < EE) {
    int pos = atomicAdd(&cursor[dst[e]], 1);
    srcs[pos] = src[e];
  }
}

// ---------------- layer-0 embedding (writes bf16 xh) ----------------
__global__ __launch_bounds__(256) void ngnn97_embed(const int* __restrict__ z, const float* __restrict__ tab,
                                                    unsigned short* __restrict__ xh) {
  int idx = blockIdx.x * 256 + threadIdx.x;
  int node = idx >> 4, c4 = (idx & 15) << 2;
  if (node < NN) {
    int zz = z[node];
    float4 v = *(const float4*)(tab + zz * 64 + c4);
    ushort4 q;
    q.x = ngnn97_f2bf(v.x); q.y = ngnn97_f2bf(v.y);
    q.z = ngnn97_f2bf(v.z); q.w = ngnn97_f2bf(v.w);
    *(ushort4*)(xh + (size_t)node * 64 + c4) = q;
  }
}

// ---------------- neighbor aggregation (bf16 gather via CSR) ----------------
__global__ __launch_bounds__(256) void ngnn97_agg(const unsigned short* __restrict__ xh,
                                                  const int* __restrict__ row_ptr,
                                                  const int* __restrict__ row_end, const int* __restrict__ srcs,
                                                  unsigned short* __restrict__ aggx) {
  int t = threadIdx.x;
  int node = blockIdx.x * 4 + (t >> 6);
  int d = t & 63;
  if (node < NN) {
    int b = row_ptr[node], e = row_end[node];
    float acc = 0.f;
    for (int i = b; i < e; i++) {
      int s = srcs[i];
      acc += ngnn97_bf2f(xh[(size_t)s * 64 + d]);
    }
    aggx[(size_t)node * 64 + d] = ngnn97_f2bf(acc);
  }
}

// ---------------- fused GRU via MFMA (+ next-layer transform) ----------------
// Block = 128 nodes, 4 waves; wave w owns strip [nbase+32w, +32) = 2 m-tiles.
// Gate GEMM: per (c,kc): 3 B-loads (R,Z,N|H — zero blocks skipped), 6 MFMAs.
// xo read from LDS (bf16). All post-barrier work is strip-local (no 2nd barrier).
__global__ __launch_bounds__(256) void ngnn97_gru(
    unsigned short* __restrict__ xh, const unsigned short* __restrict__ aggx,
    const unsigned short* __restrict__ Ubt, const float* __restrict__ Ub,
    const unsigned short* __restrict__ Vbt, const float* __restrict__ tfb,
    const int* __restrict__ z, const float* __restrict__ ztab,
    int do_transform) {
  __shared__ unsigned short Abuf[128 * 136];   // 128 rows x 136 (128 + pad) bf16, 34.8 KB
  const int t = threadIdx.x;
  const int lane = t & 63, w = t >> 6;
  const int ncol = lane & 15, quad = lane >> 4;
  const int nbase = blockIdx.x * 128;

  // ---- stage: cols 0..63 = aggx, cols 64..127 = xh ----
#pragma unroll
  for (int i = 0; i < 8; i++) {
    int chunk = i * 256 + t;                 // 0..2047
    int r = chunk >> 4, c4 = (chunk & 15) << 2;
    int node = nbase + r;
    ushort4 qa = make_ushort4(0, 0, 0, 0), qx = qa;
    if (node < NN) {
      qa = *(const ushort4*)(aggx + (size_t)node * 64 + c4);
      qx = *(const ushort4*)(xh + (size_t)node * 64 + c4);
    }
    *(ushort4*)(Abuf + r * 136 + c4) = qa;
    *(ushort4*)(Abuf + r * 136 + 64 + c4) = qx;
  }
  __syncthreads();

  // ---- A-frags: 2 m-tiles x 4 K-chunks ----
  bf16x8 afr[2][4];
#pragma unroll
  for (int mm = 0; mm < 2; mm++) {
    const unsigned short* ap = Abuf + (32 * w + mm * 16 + ncol) * 136 + quad * 8;
#pragma unroll
    for (int kc = 0; kc < 4; kc++) afr[mm][kc] = *(const bf16x8*)(ap + kc * 32);
  }

  // ---- gate GEMM + GRU update; xn written back into Abuf cols 0..63 ----
#pragma unroll
  for (int c = 0; c < 4; c++) {
    f32x4 aR[2], aZ[2], aN[2], aH[2];
#pragma unroll
    for (int mm = 0; mm < 2; mm++) {
      aR[mm] = (f32x4){0.f, 0.f, 0.f, 0.f}; aZ[mm] = aR[mm];
      aN[mm] = aR[mm]; aH[mm] = aR[mm];
    }
#pragma unroll
    for (int kc = 0; kc < 4; kc++) {
      const unsigned short* ub = Ubt + (size_t)(c * 16 + ncol) * 128 + quad * 8 + kc * 32;
      bf16x8 bR = *(const bf16x8*)(ub);
      bf16x8 bZ = *(const bf16x8*)(ub + 64 * 128);
      bf16x8 bX = (kc < 2) ? *(const bf16x8*)(ub + 128 * 128)
                           : *(const bf16x8*)(ub + 192 * 128);
#pragma unroll
      for (int mm = 0; mm < 2; mm++) {
        aR[mm] = __builtin_amdgcn_mfma_f32_16x16x32_bf16(afr[mm][kc], bR, aR[mm], 0, 0, 0);
        aZ[mm] = __builtin_amdgcn_mfma_f32_16x16x32_bf16(afr[mm][kc], bZ, aZ[mm], 0, 0, 0);
        if (kc < 2) aN[mm] = __builtin_amdgcn_mfma_f32_16x16x32_bf16(afr[mm][kc], bX, aN[mm], 0, 0, 0);
        else        aH[mm] = __builtin_amdgcn_mfma_f32_16x16x32_bf16(afr[mm][kc], bX, aH[mm], 0, 0, 0);
      }
    }
    int j = c * 16 + ncol;
    float bRs = Ub[j], bZs = Ub[64 + j], bNs = Ub[128 + j], bHs = Ub[192 + j];
#pragma unroll
    for (int mm = 0; mm < 2; mm++)
#pragma unroll
      for (int r = 0; r < 4; r++) {
        int row = 32 * w + mm * 16 + quad * 4 + r;
        float R = aR[mm][r] + bRs, Z = aZ[mm][r] + bZs;
        float Nv = aN[mm][r] + bNs, H = aH[mm][r] + bHs;
        float rg = 1.f / (1.f + __expf(-R));
        float ug = 1.f / (1.f + __expf(-Z));
        float nn2 = tanhf(Nv + rg * H);
        float xo = ngnn97_bf2f(Abuf[row * 136 + 64 + j]);
        Abuf[row * 136 + j] = ngnn97_f2bf((1.f - ug) * nn2 + ug * xo);
      }
  }

  if (do_transform) {
    // ---- embed fill: strip rows, cols 64..127 (z load is wave-uniform) ----
#pragma unroll 4
    for (int i = 0; i < 32; i++) {
      int row = 32 * w + i;
      int node = nbase + row;
      int zz = (node < NN) ? z[node] : 0;
      Abuf[row * 136 + 64 + lane] = ngnn97_f2bf(ztab[zz * 64 + lane]);
    }
    // ---- A2-frags (xn | ze) ----
    bf16x8 afr2[2][4];
#pragma unroll
    for (int mm = 0; mm < 2; mm++) {
      const unsigned short* ap2 = Abuf + (32 * w + mm * 16 + ncol) * 136 + quad * 8;
#pragma unroll
      for (int kc = 0; kc < 4; kc++) afr2[mm][kc] = *(const bf16x8*)(ap2 + kc * 32);
    }
    // ---- transform GEMM -> Abuf cols 0..63 ----
#pragma unroll
    for (int c2 = 0; c2 < 4; c2++) {
      f32x4 acc[2];
      acc[0] = (f32x4){0.f, 0.f, 0.f, 0.f}; acc[1] = acc[0];
#pragma unroll
      for (int kc = 0; kc < 4; kc++) {
        bf16x8 bV = *(const bf16x8*)(Vbt + (size_t)(c2 * 16 + ncol) * 128 + quad * 8 + kc * 32);
        acc[0] = __builtin_amdgcn_mfma_f32_16x16x32_bf16(afr2[0][kc], bV, acc[0], 0, 0, 0);
        acc[1] = __builtin_amdgcn_mfma_f32_16x16x32_bf16(afr2[1][kc], bV, acc[1], 0, 0, 0);
      }
      int j = c2 * 16 + ncol;
      float bt = tfb[j];
#pragma unroll
      for (int mm = 0; mm < 2; mm++)
#pragma unroll
        for (int r = 0; r < 4; r++) {
          int row = 32 * w + mm * 16 + quad * 4 + r;
          Abuf[row * 136 + j] = ngnn97_f2bf(acc[mm][r] + bt);
        }
    }
  }

  // ---- cooperative coalesced store: Abuf cols 0..63 (strip) -> xh ----
#pragma unroll
  for (int i = 0; i < 8; i++) {
    int chunk = i * 64 + lane;               // 0..511 over 32 rows x 16 ushort4
    int r2 = chunk >> 4, c4 = (chunk & 15) << 2;
    int row = 32 * w + r2;
    int node = nbase + row;
    if (node < NN)
      *(ushort4*)(xh + (size_t)node * 64 + c4) = *(const ushort4*)(Abuf + row * 136 + c4);
  }
}

// ---------------- pooling: sum bf16 xh rows by graph id ----------------
__global__ __launch_bounds__(256) void ngnn97_pool(const unsigned short* __restrict__ xh,
                                                   const int* __restrict__ n2s,
                                                   const int* __restrict__ s2g, float* __restrict__ gpool) {
  __shared__ float gacc[64][64];
  int t = threadIdx.x, w = t >> 6, lane = t & 63;
  for (int i = t; i < 4096; i += 256) ((float*)gacc)[i] = 0.f;
  __syncthreads();
  int base = blockIdx.x * 2048;
  for (int it = 0; it < 512; it++) {
    int node = base + it * 4 + w;
    if (node < NN) {
      int g = s2g[n2s[node]];
      atomicAdd(&gacc[g][lane], ngnn97_bf2f(xh[(size_t)node * 64 + lane]));
    }
  }
  __syncthreads();
  for (int i = t; i < 4096; i += 256) {
    float v = ((float*)gacc)[i];
    if (v != 0.f) atomicAdd(&gpool[i], v);
  }
}

// ---------------- MLP head (output: float32 [G,1]) ----------------
__global__ __launch_bounds__(256) void ngnn97_head(
    const float* __restrict__ gpool,
    const float* __restrict__ W1, const float* __restrict__ b1,
    const float* __restrict__ W2, const float* __restrict__ b2,
    const float* __restrict__ W3, const float* __restrict__ b3,
    float* __restrict__ out) {
  __shared__ float gp[4096];
  __shared__ float h1[2048];
  __shared__ float h2[1024];
  int t = threadIdx.x;
  for (int i = t; i < 4096; i += 256) gp[i] = gpool[i];
  __syncthreads();
  for (int i = t; i < 2048; i += 256) {
    int g = i >> 5, o = i & 31;
    float a = b1[o];
    for (int d = 0; d < 64; d++) a = fmaf(gp[g * 64 + d], W1[o * 64 + d], a);
    h1[i] = (a > 0.f) ? a : (__expf(a) - 1.f);
  }
  __syncthreads();
  for (int i = t; i < 1024; i += 256) {
    int g = i >> 4, o = i & 15;
    float a = b2[o];
    for (int d = 0; d < 32; d++) a = fmaf(h1[g * 32 + d], W2[o * 32 + d], a);
    h2[i] = (a > 0.f) ? a : (__expf(a) - 1.f);
  }
  __syncthreads();
  if (t < 64) {
    float a = b3[0];
    for (int d = 0; d < 16; d++) a = fmaf(h2[t * 16 + d], W3[d], a);
    out[t] = a;
  }
}

// ---------------- workspace layout (byte offsets) ----------------
// x is bf16 (xh) everywhere now; f32 x buffer eliminated. 139.4 MB total,
// well under the proven 203.8 MB budget.
#define OFF_XH   ((size_t)0)                          // N*64 bf16 = 64,000,000
#define OFF_AGG  ((size_t)64000000)                   // N*64 bf16 = 64,000,000
#define OFF_CNT  ((size_t)128000000)                  // NP int
#define OFF_ROW  (OFF_CNT + (size_t)NP * 4)
#define OFF_CUR  (OFF_ROW + (size_t)NP * 4)
#define OFF_SRC  (OFF_CUR + (size_t)NP * 4)           // E int
#define OFF_BSUM (OFF_SRC + (size_t)EE * 4)
#define OFF_BOFF (OFF_BSUM + (size_t)2048)
#define OFF_U    (OFF_BOFF + (size_t)2048)            // Ubt bf16 5*256*128
#define OFF_UB   (OFF_U + (size_t)327680)             // Ub f32 5*256
#define OFF_V    (OFF_UB + (size_t)5120)              // Vbt bf16 4*64*128
#define OFF_GP   (OFF_V + (size_t)65536)              // 64*64 f32
#define WS_NEED  (OFF_GP + (size_t)16384)             // = 139,439,936

extern "C" void kernel_launch(void* const* d_in, const int* in_sizes, int n_in,
                              void* d_out, int out_size, void* d_ws, size_t ws_size,
                              hipStream_t stream) {
  float* out = (float*)d_out;   // reference output is float32 [G,1]
  if (ws_size < WS_NEED) {
    ngnn97_code<<<1, 64, 0, stream>>>(out, 7.0f);
    return;
  }

  const int* z    = (const int*)d_in[0];
  const int* ei   = (const int*)d_in[1];
  const int* n2s  = (const int*)d_in[2];
  const int* s2g  = (const int*)d_in[3];
  const float* ztab = (const float*)d_in[4];
  const float* tfW  = (const float*)d_in[5];
  const float* tfb  = (const float*)d_in[6];
  const float* ggc  = (const float*)d_in[7];
  const float* wih  = (const float*)d_in[8];
  const float* whh  = (const float*)d_in[9];
  const float* bih  = (const float*)d_in[10];
  const float* bhh  = (const float*)d_in[11];
  const float* W1   = (const float*)d_in[12];
  const float* b1   = (const float*)d_in[13];
  const float* W2   = (const float*)d_in[14];
  const float* b2   = (const float*)d_in[15];
  const float* W3   = (const float*)d_in[16];
  const float* b3   = (const float*)d_in[17];

  char* ws = (char*)d_ws;
  unsigned short* xh     = (unsigned short*)(ws + OFF_XH);
  unsigned short* aggx   = (unsigned short*)(ws + OFF_AGG);
  int*            counts = (int*)(ws + OFF_CNT);
  int*            rowp   = (int*)(ws + OFF_ROW);
  int*            curs   = (int*)(ws + OFF_CUR);
  int*            srcs   = (int*)(ws + OFF_SRC);
  int*            bsum   = (int*)(ws + OFF_BSUM);
  int*            boff   = (int*)(ws + OFF_BOFF);
  unsigned short* Ubt    = (unsigned short*)(ws + OFF_U);
  float*          Ub     = (float*)(ws + OFF_UB);
  unsigned short* Vbt    = (unsigned short*)(ws + OFF_V);
  float*          gpool  = (float*)(ws + OFF_GP);

  hipMemsetAsync(counts, 0, (size_t)NP * 4, stream);
  hipMemsetAsync(gpool, 0, 16384, stream);

  ngnn97_pre<<<774, 256, 0, stream>>>(ggc, wih, whh, bih, bhh, tfW, Ubt, Ub, Vbt);

  // CSR by dst
  const int* srcp = ei;
  const int* dstp = ei + EE;
  ngnn97_hist<<<(EE + 255) / 256, 256, 0, stream>>>(dstp, counts);
  ngnn97_red<<<NBLK, 256, 0, stream>>>(counts, bsum);
  ngnn97_scan1<<<1, 512, 0, stream>>>(bsum, boff);
  ngnn97_scan2<<<NBLK, 256, 0, stream>>>(counts, boff, rowp, curs);
  ngnn97_fill<<<(EE + 255) / 256, 256, 0, stream>>>(srcp, dstp, curs, srcs);
  // after ngnn97_fill, curs[i] == row end

  ngnn97_embed<<<(NN * 16 + 255) / 256, 256, 0, stream>>>(z, ztab, xh);

  for (int l = 0; l < 5; l++) {
    ngnn97_agg<<<(NN + 3) / 4, 256, 0, stream>>>(xh, rowp, curs, srcs, aggx);
    ngnn97_gru<<<(NN + 127) / 128, 256, 0, stream>>>(
        xh, aggx, Ubt + (size_t)l * 32768, Ub + (size_t)l * 256,
        Vbt + (size_t)(l < 4 ? l : 0) * 8192, tfb + (size_t)(l < 4 ? l : 0) * 64,
        z, ztab + (size_t)(l < 4 ? l + 1 : 0) * 6400, (l < 4) ? 1 : 0);
  }

  ngnn97_pool<<<(NN + 2047) / 2048, 256, 0, stream>>>(xh, n2s, s2g, gpool);
  ngnn97_head<<<1, 256, 0, stream>>>(gpool, W1, b1, W2, b2, W3, b3, out);
}

// Round 11
// 2063.698 us; speedup vs baseline: 1.8268x; 1.0238x over previous
//
#include <hip/hip_runtime.h>
#include <hip/hip_bf16.h>

// ---------------- problem constants ----------------
#define NN 500000
#define EE 1250000
#define NP 501760          // padded node count
#define NBLK 489           // scan blocks of 1024

typedef __attribute__((ext_vector_type(8))) short bf16x8;
typedef __attribute__((ext_vector_type(4))) float f32x4;

__device__ __forceinline__ float ngnn97_bf2f(unsigned short u) {
  return __uint_as_float(((unsigned int)u) << 16);
}
__device__ __forceinline__ unsigned short ngnn97_f2bf(float f) {
  union { __hip_bfloat16 b; unsigned short u; } cv;
  cv.b = __float2bfloat16(f);
  return cv.u;
}

// ---------------- diagnostic code writer (guard path only) ----------------
__global__ void ngnn97_code(float* __restrict__ out, float v) {
  if (threadIdx.x < 64) out[threadIdx.x] = v;
}

// ---------------- precompute folded weights (bf16, MFMA-B layout) ----------------
__global__ __launch_bounds__(256) void ngnn97_pre(
    const float* __restrict__ ggc, const float* __restrict__ wih,
    const float* __restrict__ whh, const float* __restrict__ bih,
    const float* __restrict__ bhh, const float* __restrict__ tfW,
    unsigned short* __restrict__ Ubt, float* __restrict__ Ub,
    unsigned short* __restrict__ Vbt) {
  int idx = blockIdx.x * 256 + threadIdx.x;
  if (idx < 163840) {                      // Ubt: 5*256*128
    int l = idx >> 15, r = idx & 32767;
    int n = r >> 7, k = r & 127;
    float v = 0.f;
    if (k < 64) {
      if (n < 192) {
        const float* gp = ggc + l * 4096 + k * 64;
        const float* wp = wih + l * 12288 + n * 64;
        float acc = 0.f;
#pragma unroll
        for (int t2 = 0; t2 < 64; t2++) acc = fmaf(gp[t2], wp[t2], acc);
        v = acc;
      }
    } else {
      int k2 = k - 64;
      if (n < 128) v = whh[l * 12288 + n * 64 + k2];
      else if (n >= 192) v = whh[l * 12288 + (n - 64) * 64 + k2];
    }
    Ubt[idx] = ngnn97_f2bf(v);
  } else if (idx < 163840 + 32768) {       // Vbt: 4*64*128 (= tfW flat)
    int i2 = idx - 163840;
    Vbt[i2] = ngnn97_f2bf(tfW[i2]);
  } else if (idx < 163840 + 32768 + 1280) { // Ub: 5*256
    int i2 = idx - 196608;
    int l = i2 >> 8, j = i2 & 255;
    float v;
    if (j < 128)      v = bih[l * 192 + j] + bhh[l * 192 + j];
    else if (j < 192) v = bih[l * 192 + j];
    else              v = bhh[l * 192 + j - 64];
    Ub[i2] = v;
  }
}

// ---------------- CSR build ----------------
__global__ __launch_bounds__(256) void ngnn97_hist(const int* __restrict__ dst, int* __restrict__ counts) {
  int e = blockIdx.x * 256 + threadIdx.x;
  if (e < EE) atomicAdd(&counts[dst[e]], 1);
}

__global__ __launch_bounds__(256) void ngnn97_red(const int* __restrict__ counts, int* __restrict__ bsum) {
  __shared__ int s[256];
  int t = threadIdx.x, base = blockIdx.x * 1024;
  int v = 0;
#pragma unroll
  for (int i = 0; i < 4; i++) v += counts[base + t + i * 256];
  s[t] = v; __syncthreads();
  for (int o = 128; o > 0; o >>= 1) { if (t < o) s[t] += s[t + o]; __syncthreads(); }
  if (t == 0) bsum[blockIdx.x] = s[0];
}

__global__ __launch_bounds__(512) void ngnn97_scan1(const int* __restrict__ bsum, int* __restrict__ boff) {
  __shared__ int s[512];
  int t = threadIdx.x;
  int v = (t < NBLK) ? bsum[t] : 0;
  s[t] = v; __syncthreads();
  for (int o = 1; o < 512; o <<= 1) {
    int a = (t >= o) ? s[t - o] : 0;
    __syncthreads(); s[t] += a; __syncthreads();
  }
  if (t < NBLK) boff[t] = s[t] - v;   // exclusive
}

__global__ __launch_bounds__(256) void ngnn97_scan2(const int* __restrict__ counts, const int* __restrict__ boff,
                                                    int* __restrict__ row_ptr, int* __restrict__ cursor) {
  __shared__ int s[256];
  int t = threadIdx.x, base = blockIdx.x * 1024;
  int4 c = *(const int4*)(counts + base + t * 4);
  int tsum = c.x + c.y + c.z + c.w;
  s[t] = tsum; __syncthreads();
  for (int o = 1; o < 256; o <<= 1) {
    int a = (t >= o) ? s[t - o] : 0;
    __syncthreads(); s[t] += a; __syncthreads();
  }
  int off = boff[blockIdx.x] + s[t] - tsum;
  int4 r;
  r.x = off; r.y = off + c.x; r.z = off + c.x + c.y; r.w = off + c.x + c.y + c.z;
  *(int4*)(row_ptr + base + t * 4) = r;
  *(int4*)(cursor + base + t * 4) = r;
}

__global__ __launch_bounds__(256) void ngnn97_fill(const int* __restrict__ src, const int* __restrict__ dst,
                                                   int* __restrict__ cursor, int* __restrict__ srcs) {
  int e = blockIdx.x * 256 + threadIdx.x;
  if (e < EE) {
    int pos = atomicAdd(&cursor[dst[e]], 1);
    srcs[pos] = src[e];
  }
}

// ---------------- node -> graph id precompute (uint8) ----------------
__global__ __launch_bounds__(256) void ngnn97_g8(const int* __restrict__ n2s, const int* __restrict__ s2g,
                                                 unsigned char* __restrict__ g8) {
  int idx = blockIdx.x * 256 + threadIdx.x;
  if (idx < NN) g8[idx] = (unsigned char)s2g[n2s[idx]];
}

// ---------------- layer-0 embedding (writes bf16 xh) ----------------
__global__ __launch_bounds__(256) void ngnn97_embed(const int* __restrict__ z, const float* __restrict__ tab,
                                                    unsigned short* __restrict__ xh) {
  int idx = blockIdx.x * 256 + threadIdx.x;
  int node = idx >> 4, c4 = (idx & 15) << 2;
  if (node < NN) {
    int zz = z[node];
    float4 v = *(const float4*)(tab + zz * 64 + c4);
    ushort4 q;
    q.x = ngnn97_f2bf(v.x); q.y = ngnn97_f2bf(v.y);
    q.z = ngnn97_f2bf(v.z); q.w = ngnn97_f2bf(v.w);
    *(ushort4*)(xh + (size_t)node * 64 + c4) = q;
  }
}

// ---------------- neighbor aggregation (bf16 gather via CSR) ----------------
__global__ __launch_bounds__(256) void ngnn97_agg(const unsigned short* __restrict__ xh,
                                                  const int* __restrict__ row_ptr,
                                                  const int* __restrict__ row_end, const int* __restrict__ srcs,
                                                  unsigned short* __restrict__ aggx) {
  int t = threadIdx.x;
  int node = blockIdx.x * 4 + (t >> 6);
  int d = t & 63;
  if (node < NN) {
    int b = row_ptr[node], e = row_end[node];
    float acc = 0.f;
    for (int i = b; i < e; i++) {
      int s = srcs[i];
      acc += ngnn97_bf2f(xh[(size_t)s * 64 + d]);
    }
    aggx[(size_t)node * 64 + d] = ngnn97_f2bf(acc);
  }
}

// ---------------- fused GRU via MFMA (+ next-layer transform) ----------------
__global__ __launch_bounds__(256) void ngnn97_gru(
    unsigned short* __restrict__ xh, const unsigned short* __restrict__ aggx,
    const unsigned short* __restrict__ Ubt, const float* __restrict__ Ub,
    const unsigned short* __restrict__ Vbt, const float* __restrict__ tfb,
    const int* __restrict__ z, const float* __restrict__ ztab,
    int do_transform) {
  __shared__ unsigned short Abuf[128 * 136];   // 128 rows x (128 + pad 8) bf16, 34.8 KB
  const int t = threadIdx.x;
  const int lane = t & 63, w = t >> 6;
  const int ncol = lane & 15, quad = lane >> 4;
  const int nbase = blockIdx.x * 128;

  // ---- stage: cols 0..63 = aggx, cols 64..127 = xh ----
#pragma unroll
  for (int i = 0; i < 8; i++) {
    int chunk = i * 256 + t;                 // 0..2047
    int r = chunk >> 4, c4 = (chunk & 15) << 2;
    int node = nbase + r;
    ushort4 qa = make_ushort4(0, 0, 0, 0), qx = qa;
    if (node < NN) {
      qa = *(const ushort4*)(aggx + (size_t)node * 64 + c4);
      qx = *(const ushort4*)(xh + (size_t)node * 64 + c4);
    }
    *(ushort4*)(Abuf + r * 136 + c4) = qa;
    *(ushort4*)(Abuf + r * 136 + 64 + c4) = qx;
  }
  __syncthreads();

  // ---- A-frags: 2 m-tiles x 4 K-chunks ----
  bf16x8 afr[2][4];
#pragma unroll
  for (int mm = 0; mm < 2; mm++) {
    const unsigned short* ap = Abuf + (32 * w + mm * 16 + ncol) * 136 + quad * 8;
#pragma unroll
    for (int kc = 0; kc < 4; kc++) afr[mm][kc] = *(const bf16x8*)(ap + kc * 32);
  }

  // ---- gate GEMM + GRU update; xn written back into Abuf cols 0..63 ----
#pragma unroll
  for (int c = 0; c < 4; c++) {
    f32x4 aR[2], aZ[2], aN[2], aH[2];
#pragma unroll
    for (int mm = 0; mm < 2; mm++) {
      aR[mm] = (f32x4){0.f, 0.f, 0.f, 0.f}; aZ[mm] = aR[mm];
      aN[mm] = aR[mm]; aH[mm] = aR[mm];
    }
#pragma unroll
    for (int kc = 0; kc < 4; kc++) {
      const unsigned short* ub = Ubt + (size_t)(c * 16 + ncol) * 128 + quad * 8 + kc * 32;
      bf16x8 bR = *(const bf16x8*)(ub);
      bf16x8 bZ = *(const bf16x8*)(ub + 64 * 128);
      bf16x8 bX = (kc < 2) ? *(const bf16x8*)(ub + 128 * 128)
                           : *(const bf16x8*)(ub + 192 * 128);
#pragma unroll
      for (int mm = 0; mm < 2; mm++) {
        aR[mm] = __builtin_amdgcn_mfma_f32_16x16x32_bf16(afr[mm][kc], bR, aR[mm], 0, 0, 0);
        aZ[mm] = __builtin_amdgcn_mfma_f32_16x16x32_bf16(afr[mm][kc], bZ, aZ[mm], 0, 0, 0);
        if (kc < 2) aN[mm] = __builtin_amdgcn_mfma_f32_16x16x32_bf16(afr[mm][kc], bX, aN[mm], 0, 0, 0);
        else        aH[mm] = __builtin_amdgcn_mfma_f32_16x16x32_bf16(afr[mm][kc], bX, aH[mm], 0, 0, 0);
      }
    }
    int j = c * 16 + ncol;
    float bRs = Ub[j], bZs = Ub[64 + j], bNs = Ub[128 + j], bHs = Ub[192 + j];
#pragma unroll
    for (int mm = 0; mm < 2; mm++)
#pragma unroll
      for (int r = 0; r < 4; r++) {
        int row = 32 * w + mm * 16 + quad * 4 + r;
        float R = aR[mm][r] + bRs, Z = aZ[mm][r] + bZs;
        float Nv = aN[mm][r] + bNs, H = aH[mm][r] + bHs;
        float rg = 1.f / (1.f + __expf(-R));
        float ug = 1.f / (1.f + __expf(-Z));
        float nn2 = tanhf(Nv + rg * H);
        float xo = ngnn97_bf2f(Abuf[row * 136 + 64 + j]);
        Abuf[row * 136 + j] = ngnn97_f2bf((1.f - ug) * nn2 + ug * xo);
      }
  }

  if (do_transform) {
#pragma unroll 4
    for (int i = 0; i < 32; i++) {
      int row = 32 * w + i;
      int node = nbase + row;
      int zz = (node < NN) ? z[node] : 0;
      Abuf[row * 136 + 64 + lane] = ngnn97_f2bf(ztab[zz * 64 + lane]);
    }
    bf16x8 afr2[2][4];
#pragma unroll
    for (int mm = 0; mm < 2; mm++) {
      const unsigned short* ap2 = Abuf + (32 * w + mm * 16 + ncol) * 136 + quad * 8;
#pragma unroll
      for (int kc = 0; kc < 4; kc++) afr2[mm][kc] = *(const bf16x8*)(ap2 + kc * 32);
    }
#pragma unroll
    for (int c2 = 0; c2 < 4; c2++) {
      f32x4 acc[2];
      acc[0] = (f32x4){0.f, 0.f, 0.f, 0.f}; acc[1] = acc[0];
#pragma unroll
      for (int kc = 0; kc < 4; kc++) {
        bf16x8 bV = *(const bf16x8*)(Vbt + (size_t)(c2 * 16 + ncol) * 128 + quad * 8 + kc * 32);
        acc[0] = __builtin_amdgcn_mfma_f32_16x16x32_bf16(afr2[0][kc], bV, acc[0], 0, 0, 0);
        acc[1] = __builtin_amdgcn_mfma_f32_16x16x32_bf16(afr2[1][kc], bV, acc[1], 0, 0, 0);
      }
      int j = c2 * 16 + ncol;
      float bt = tfb[j];
#pragma unroll
      for (int mm = 0; mm < 2; mm++)
#pragma unroll
        for (int r = 0; r < 4; r++) {
          int row = 32 * w + mm * 16 + quad * 4 + r;
          Abuf[row * 136 + j] = ngnn97_f2bf(acc[mm][r] + bt);
        }
    }
  }

  // ---- cooperative coalesced store: Abuf cols 0..63 (strip) -> xh ----
#pragma unroll
  for (int i = 0; i < 8; i++) {
    int chunk = i * 64 + lane;               // 0..511 over 32 rows x 16 ushort4
    int r2 = chunk >> 4, c4 = (chunk & 15) << 2;
    int row = 32 * w + r2;
    int node = nbase + row;
    if (node < NN)
      *(ushort4*)(xh + (size_t)node * 64 + c4) = *(const ushort4*)(Abuf + row * 136 + c4);
  }
}

// ---------------- pooling stage 1: 256 nodes/block, partial sums into 256 slots ----------------
__global__ __launch_bounds__(256) void ngnn97_pool(const unsigned short* __restrict__ xh,
                                                   const unsigned char* __restrict__ g8,
                                                   float* __restrict__ gpart) {
  __shared__ float gacc[64][64];
  int t = threadIdx.x, w = t >> 6, lane = t & 63;
  for (int i = t; i < 4096; i += 256) ((float*)gacc)[i] = 0.f;
  __syncthreads();
  int base = blockIdx.x * 256;
#pragma unroll 4
  for (int it = 0; it < 64; it++) {
    int node = base + it * 4 + w;
    if (node < NN) {
      int g = g8[node];
      atomicAdd(&gacc[g][lane], ngnn97_bf2f(xh[(size_t)node * 64 + lane]));
    }
  }
  __syncthreads();
  float* slot = gpart + (size_t)(blockIdx.x & 255) * 4096;
  for (int i = t; i < 4096; i += 256) {
    float v = ((float*)gacc)[i];
    if (v != 0.f) atomicAdd(&slot[i], v);
  }
}

// ---------------- pooling stage 2: fold 256 slots -> gpool ----------------
__global__ __launch_bounds__(256) void ngnn97_reduce(const float* __restrict__ gpart,
                                                     float* __restrict__ gpool) {
  int i = blockIdx.x * 256 + threadIdx.x;    // 0..4095
  float s = 0.f;
#pragma unroll 8
  for (int k = 0; k < 256; k++) s += gpart[(size_t)k * 4096 + i];
  gpool[i] = s;
}

// ---------------- MLP head (output: float32 [G,1]) ----------------
__global__ __launch_bounds__(256) void ngnn97_head(
    const float* __restrict__ gpool,
    const float* __restrict__ W1, const float* __restrict__ b1,
    const float* __restrict__ W2, const float* __restrict__ b2,
    const float* __restrict__ W3, const float* __restrict__ b3,
    float* __restrict__ out) {
  __shared__ float gp[4096];
  __shared__ float h1[2048];
  __shared__ float h2[1024];
  int t = threadIdx.x;
  for (int i = t; i < 4096; i += 256) gp[i] = gpool[i];
  __syncthreads();
  for (int i = t; i < 2048; i += 256) {
    int g = i >> 5, o = i & 31;
    float a = b1[o];
    for (int d = 0; d < 64; d++) a = fmaf(gp[g * 64 + d], W1[o * 64 + d], a);
    h1[i] = (a > 0.f) ? a : (__expf(a) - 1.f);
  }
  __syncthreads();
  for (int i = t; i < 1024; i += 256) {
    int g = i >> 4, o = i & 15;
    float a = b2[o];
    for (int d = 0; d < 32; d++) a = fmaf(h1[g * 32 + d], W2[o * 32 + d], a);
    h2[i] = (a > 0.f) ? a : (__expf(a) - 1.f);
  }
  __syncthreads();
  if (t < 64) {
    float a = b3[0];
    for (int d = 0; d < 16; d++) a = fmaf(h2[t * 16 + d], W3[d], a);
    out[t] = a;
  }
}

// ---------------- workspace layout (byte offsets) ----------------
// 144 MB total, well under the proven 203.8 MB budget.
#define OFF_XH    ((size_t)0)                          // N*64 bf16 = 64,000,000
#define OFF_AGG   ((size_t)64000000)                   // N*64 bf16 = 64,000,000
#define OFF_CNT   ((size_t)128000000)                  // NP int
#define OFF_ROW   (OFF_CNT + (size_t)NP * 4)
#define OFF_CUR   (OFF_ROW + (size_t)NP * 4)
#define OFF_SRC   (OFF_CUR + (size_t)NP * 4)           // E int
#define OFF_BSUM  (OFF_SRC + (size_t)EE * 4)
#define OFF_BOFF  (OFF_BSUM + (size_t)2048)
#define OFF_U     (OFF_BOFF + (size_t)2048)            // Ubt bf16 5*256*128
#define OFF_UB    (OFF_U + (size_t)327680)             // Ub f32 5*256
#define OFF_V     (OFF_UB + (size_t)5120)              // Vbt bf16 4*64*128
#define OFF_GP    (OFF_V + (size_t)65536)              // gpool 64*64 f32
#define OFF_G8    (OFF_GP + (size_t)16384)             // N uint8 (padded)
#define OFF_GPART (OFF_G8 + (size_t)500736)            // 256*4096 f32 = 4 MB
#define WS_NEED   (OFF_GPART + (size_t)4194304)        // = 144,151,360

extern "C" void kernel_launch(void* const* d_in, const int* in_sizes, int n_in,
                              void* d_out, int out_size, void* d_ws, size_t ws_size,
                              hipStream_t stream) {
  float* out = (float*)d_out;   // reference output is float32 [G,1]
  if (ws_size < WS_NEED) {
    ngnn97_code<<<1, 64, 0, stream>>>(out, 7.0f);
    return;
  }

  const int* z    = (const int*)d_in[0];
  const int* ei   = (const int*)d_in[1];
  const int* n2s  = (const int*)d_in[2];
  const int* s2g  = (const int*)d_in[3];
  const float* ztab = (const float*)d_in[4];
  const float* tfW  = (const float*)d_in[5];
  const float* tfb  = (const float*)d_in[6];
  const float* ggc  = (const float*)d_in[7];
  const float* wih  = (const float*)d_in[8];
  const float* whh  = (const float*)d_in[9];
  const float* bih  = (const float*)d_in[10];
  const float* bhh  = (const float*)d_in[11];
  const float* W1   = (const float*)d_in[12];
  const float* b1   = (const float*)d_in[13];
  const float* W2   = (const float*)d_in[14];
  const float* b2   = (const float*)d_in[15];
  const float* W3   = (const float*)d_in[16];
  const float* b3   = (const float*)d_in[17];

  char* ws = (char*)d_ws;
  unsigned short* xh     = (unsigned short*)(ws + OFF_XH);
  unsigned short* aggx   = (unsigned short*)(ws + OFF_AGG);
  int*            counts = (int*)(ws + OFF_CNT);
  int*            rowp   = (int*)(ws + OFF_ROW);
  int*            curs   = (int*)(ws + OFF_CUR);
  int*            srcs   = (int*)(ws + OFF_SRC);
  int*            bsum   = (int*)(ws + OFF_BSUM);
  int*            boff   = (int*)(ws + OFF_BOFF);
  unsigned short* Ubt    = (unsigned short*)(ws + OFF_U);
  float*          Ub     = (float*)(ws + OFF_UB);
  unsigned short* Vbt    = (unsigned short*)(ws + OFF_V);
  float*          gpool  = (float*)(ws + OFF_GP);
  unsigned char*  g8     = (unsigned char*)(ws + OFF_G8);
  float*          gpart  = (float*)(ws + OFF_GPART);

  hipMemsetAsync(counts, 0, (size_t)NP * 4, stream);
  hipMemsetAsync(gpart, 0, (size_t)4194304, stream);

  ngnn97_pre<<<774, 256, 0, stream>>>(ggc, wih, whh, bih, bhh, tfW, Ubt, Ub, Vbt);
  ngnn97_g8<<<(NN + 255) / 256, 256, 0, stream>>>(n2s, s2g, g8);

  // CSR by dst
  const int* srcp = ei;
  const int* dstp = ei + EE;
  ngnn97_hist<<<(EE + 255) / 256, 256, 0, stream>>>(dstp, counts);
  ngnn97_red<<<NBLK, 256, 0, stream>>>(counts, bsum);
  ngnn97_scan1<<<1, 512, 0, stream>>>(bsum, boff);
  ngnn97_scan2<<<NBLK, 256, 0, stream>>>(counts, boff, rowp, curs);
  ngnn97_fill<<<(EE + 255) / 256, 256, 0, stream>>>(srcp, dstp, curs, srcs);
  // after ngnn97_fill, curs[i] == row end

  ngnn97_embed<<<(NN * 16 + 255) / 256, 256, 0, stream>>>(z, ztab, xh);

  for (int l = 0; l < 5; l++) {
    ngnn97_agg<<<(NN + 3) / 4, 256, 0, stream>>>(xh, rowp, curs, srcs, aggx);
    ngnn97_gru<<<(NN + 127) / 128, 256, 0, stream>>>(
        xh, aggx, Ubt + (size_t)l * 32768, Ub + (size_t)l * 256,
        Vbt + (size_t)(l < 4 ? l : 0) * 8192, tfb + (size_t)(l < 4 ? l : 0) * 64,
        z, ztab + (size_t)(l < 4 ? l + 1 : 0) * 6400, (l < 4) ? 1 : 0);
  }

  ngnn97_pool<<<(NN + 255) / 256, 256, 0, stream>>>(xh, g8, gpart);
  ngnn97_reduce<<<16, 256, 0, stream>>>(gpart, gpool);
  ngnn97_head<<<1, 256, 0, stream>>>(gpool, W1, b1, W2, b2, W3, b3, out);
}